// Round 6
// baseline (320.997 us; speedup 1.0000x reference)
//
#include <hip/hip_runtime.h>

#define B_ 4
#define T_ 4096
#define D_ 1024
#define R_ (B_*T_)
#define CHUNK_ 64
#define NCH_ (T_/CHUNK_)
#define EPS_ 1.1920929e-07f
#define P_ ((size_t)R_*64)   // elements per 64-col activation plane

typedef unsigned short ushort_t;
typedef __attribute__((ext_vector_type(8))) short short8;
typedef __attribute__((ext_vector_type(4))) float f32x4;

__device__ __forceinline__ float silu_f(float v){ return v / (1.0f + __expf(-v)); }

__device__ __forceinline__ ushort_t f2bf(float f){
    unsigned u = __float_as_uint(f);
    unsigned r = u + 0x7fffu + ((u>>16)&1u);
    return (ushort_t)(r>>16);
}
__device__ __forceinline__ float bf2f(ushort_t s){ return __uint_as_float(((unsigned)s)<<16); }

__device__ __forceinline__ f32x4 mfma16(short8 a, short8 b, f32x4 c){
    return __builtin_amdgcn_mfma_f32_16x16x32_bf16(a, b, c, 0, 0, 0);
}

// bf16 activations (e, hsum, h) use tiled layout [n:16][row:R_][col:64].
// r is NEVER materialized in global memory: post+rlow+out fused in por_k,
// r lives in LDS per 16-row block (saves 96 MB HBM + 2 launches).

// ---------------- prep: weight cvt (bf16) + scalar setup ----------------
__global__ void prep_k(const float* __restrict__ s0, const float* __restrict__ s1,
                       const float* __restrict__ s2, const float* __restrict__ s3,
                       const float* __restrict__ s4, const float* __restrict__ s5,
                       ushort_t* __restrict__ d0, ushort_t* __restrict__ d1,
                       ushort_t* __restrict__ d2, ushort_t* __restrict__ d3,
                       ushort_t* __restrict__ d4, ushort_t* __restrict__ d5,
                       const float* __restrict__ logA_seq, const float* __restrict__ logdt_seq,
                       const float* __restrict__ logA_dep, const float* __restrict__ logdt_dep,
                       const int* __restrict__ active_k,
                       float* __restrict__ aseq, float* __restrict__ apowC, float* __restrict__ gain){
    int i = blockIdx.x*256 + threadIdx.x;
    if      (i < 65536)   d0[i] = f2bf(s0[i]);
    else if (i < 131072)  d1[i-65536] = f2bf(s1[i-65536]);
    else if (i < 327680)  d2[i-131072] = f2bf(s2[i-131072]);
    else if (i < 393216)  d3[i-327680] = f2bf(s3[i-327680]);
    else if (i < 458752)  d4[i-393216] = f2bf(s4[i-393216]);
    else if (i < 524288)  d5[i-458752] = f2bf(s5[i-458752]);
    else if (i < 524288 + D_){
        int d = i - 524288;
        float K = (float)(*active_k);
        float a = expf(-expf(logA_seq[d]) * expf(logdt_seq[d]));
        a = fmaxf(a, 1e-6f);
        aseq[d] = a;
        apowC[d] = powf(a, (float)CHUNK_);
        float g;
        if (d < 128) {
            g = K;
        } else {
            float ad = expf(-expf(logA_dep[d-128]) * expf(logdt_dep[d-128]));
            float om = 1.0f - ad;
            if (fabsf(om) < 1e-6f) g = K;
            else g = (1.0f - powf(ad, K)) / fmaxf(om, 1e-8f);
        }
        gain[d] = g;
    }
}

// ---------------- rms_norm(x) -> e bf16 (tiled store) ----------------
__global__ __launch_bounds__(256) void rmsbf_k(const float* __restrict__ x, ushort_t* __restrict__ e){
    int row = blockIdx.x;
    int tid = threadIdx.x;
    float4 v = ((const float4*)(x + (size_t)row*D_))[tid];
    float ss = v.x*v.x + v.y*v.y + v.z*v.z + v.w*v.w;
    for (int off=32; off; off>>=1) ss += __shfl_down(ss, off, 64);
    __shared__ float red[4];
    if ((tid&63)==0) red[tid>>6] = ss;
    __syncthreads();
    float tot = red[0]+red[1]+red[2]+red[3];
    float scale = 1.0f / sqrtf(tot*(1.0f/D_) + EPS_);
    ushort4 o;
    o.x = f2bf(v.x*scale); o.y = f2bf(v.y*scale); o.z = f2bf(v.z*scale); o.w = f2bf(v.w*scale);
    int col = tid*4;
    *(ushort4*)(e + (size_t)(col>>6)*P_ + (size_t)row*64 + (col&63)) = o;
}

// ---------------- bd2s: blockdiags + fused local chunk scan (tiled io) ----------------
__global__ __launch_bounds__(256) void bd2s_k(const ushort_t* __restrict__ e,
        const ushort_t* __restrict__ wseq, const ushort_t* __restrict__ wdep,
        const float* __restrict__ gain, const float* __restrict__ aseq,
        ushort_t* __restrict__ hsum, float* __restrict__ carry){
    __shared__ __align__(16) ushort_t sd[4][16][72];
    __shared__ __align__(16) ushort_t sh[4][16][72];
    int wave = threadIdx.x>>6, lane = threadIdx.x&63;
    int m = lane&15, quad = lane>>4;
    int orow = lane>>2, oq = lane&3;
    int n = blockIdx.y;
    int chunk0 = blockIdx.x*256 + wave*64;

    short8 bs[2][4], bd[2][4];
    #pragma unroll
    for (int s=0;s<2;++s)
        #pragma unroll
        for (int c=0;c<4;++c){
            bs[s][c] = *(const short8*)(wseq + n*4096 + (c*16+m)*64 + s*32 + quad*8);
            bd[s][c] = *(const short8*)(wdep + n*4096 + (c*16+m)*64 + s*32 + quad*8);
        }
    float g[4];
    #pragma unroll
    for (int c=0;c<4;++c) g[c] = gain[n*64 + c*16 + m];

    float a = aseq[n*64 + lane];
    float hh = 0.f;

    #pragma unroll
    for (int t=0;t<4;++t){
        int r0 = chunk0 + t*16;
        const ushort_t* ab = e + (size_t)n*P_ + (size_t)(r0+m)*64 + quad*8;
        short8 a0 = *(const short8*)ab;
        short8 a1 = *(const short8*)(ab + 32);
        f32x4 accs[4], accd[4];
        #pragma unroll
        for (int c=0;c<4;++c){
            accs[c]=(f32x4)0.f; accd[c]=(f32x4)0.f;
            accs[c]=mfma16(a0, bs[0][c], accs[c]);
            accd[c]=mfma16(a0, bd[0][c], accd[c]);
            accs[c]=mfma16(a1, bs[1][c], accs[c]);
            accd[c]=mfma16(a1, bd[1][c], accd[c]);
        }
        #pragma unroll
        for (int c=0;c<4;++c)
            #pragma unroll
            for (int r=0;r<4;++r){
                sd[wave][quad*4+r][c*16+m] = f2bf(silu_f(accs[c][r]));
                sh[wave][quad*4+r][c*16+m] = f2bf(g[c]*silu_f(accd[c][r]));
            }
        #pragma unroll
        for (int s=0;s<16;++s){
            hh = fmaf(a, hh, bf2f(sd[wave][s][lane]));
            sd[wave][s][lane] = f2bf(hh + bf2f(sh[wave][s][lane]));
        }
        ushort_t* db = hsum + (size_t)n*P_ + (size_t)(r0+orow)*64;
        #pragma unroll
        for (int it=0;it<2;++it)
            *(short8*)(db + (it*4+oq)*8) = *(const short8*)&sd[wave][orow][(it*4+oq)*8];
    }
    carry[(size_t)(chunk0>>6)*D_ + n*64 + lane] = hh;
}

// ---------------- scan2: serial prefix over chunk carries ----------------
__global__ __launch_bounds__(256) void scan2_k(float* __restrict__ carry, const float* __restrict__ apowC){
    int tid = blockIdx.x*256 + threadIdx.x;      // B_*D_ threads
    int d = tid & (D_-1);
    int b = tid >> 10;
    float aC = apowC[d];
    float pref = 0.f;
    for (int c=0;c<NCH_;++c){
        size_t idx = (size_t)(b*NCH_+c)*D_ + d;
        float s = carry[idx];
        carry[idx] = pref;
        pref = fmaf(aC, pref, s);
    }
}

// ---------------- scan3: h = hsum + P*a^(s+1) -> bf16, vectorized (8 ch/thread) ----------------
__global__ __launch_bounds__(256) void scan3_k(const ushort_t* __restrict__ hsum,
                                               const float* __restrict__ aseq,
                                               const float* __restrict__ carry,
                                               ushort_t* __restrict__ h){
    int tid = blockIdx.x*256 + threadIdx.x;   // 32768 threads total
    int d0g  = (tid&7)*8;                     // within-plane col base
    int trip = tid>>3;                        // bc*16 + n
    int n  = trip & 15;
    int bc = trip >> 4;                       // b*NCH_ + c
    int b  = bc >> 6;
    int c  = bc & (NCH_-1);
    int d  = n*64 + d0g;
    float a[8], P[8], apow[8];
    #pragma unroll
    for (int j=0;j<8;++j){
        a[j] = aseq[d+j];
        P[j] = carry[(size_t)bc*D_ + d + j];
        apow[j] = a[j];
    }
    size_t base = (size_t)n*P_ + (size_t)(b*T_ + c*CHUNK_)*64 + d0g;
    for (int s=0; s<CHUNK_; ++s){
        short8 v = *(const short8*)(hsum + base + (size_t)s*64);
        short8 o;
        #pragma unroll
        for (int j=0;j<8;++j){
            o[j] = (short)f2bf(bf2f((ushort_t)v[j]) + P[j]*apow[j]);
            apow[j] *= a[j];
        }
        *(short8*)(h + base + (size_t)s*64) = o;
    }
}

// ---------------- scale[row] = rsqrt(mean(h^2)+eps) ----------------
__global__ __launch_bounds__(256) void scale_k(const ushort_t* __restrict__ h, float* __restrict__ scale){
    int wave = threadIdx.x>>6, lane = threadIdx.x&63;
    int row = blockIdx.x*4 + wave;
    int pl = lane>>2, q = lane&3;
    const ushort_t* hb = h + (size_t)pl*P_ + (size_t)row*64 + q*16;
    short8 v0 = *(const short8*)hb;
    short8 v1 = *(const short8*)(hb + 8);
    float ss = 0.f;
    #pragma unroll
    for (int j=0;j<8;++j){ float f0 = bf2f((ushort_t)v0[j]); float f1 = bf2f((ushort_t)v1[j]); ss += f0*f0 + f1*f1; }
    for (int off=32; off; off>>=1) ss += __shfl_down(ss, off, 64);
    if (lane==0) scale[row] = rsqrtf(ss*(1.0f/D_) + EPS_);
}

// ---------------- por: fused post + rlow + out for one 16-row tile ----------------
// phase1: r = silu(concat[h*scale,e,eshift] @ wpost^T) -> LDS (never global)
// phase2: rlow = r @ lrB^T (split-K over 4 waves, LDS reduce)
// phase3: out = x + r@wloc^T + rlow@lrA^T  (each wave: 4 n-blocks)
__global__ __launch_bounds__(256) void por_k(const float* __restrict__ x,
        const ushort_t* __restrict__ h, const float* __restrict__ scale,
        const ushort_t* __restrict__ e, const ushort_t* __restrict__ wpost,
        const ushort_t* __restrict__ lrB, const ushort_t* __restrict__ wloc,
        const ushort_t* __restrict__ lrA, float* __restrict__ out){
    __shared__ __align__(16) ushort_t r_lds[16][1032];   // 33 KB, padded: row stride 2064B -> 2-way banks
    __shared__ __align__(16) float sacc[4][16][68];      // 17.4 KB (rlow partials; reused as out staging)
    __shared__ __align__(16) ushort_t rl_lds[16][72];    // 2.3 KB
    int wave = threadIdx.x>>6, lane = threadIdx.x&63;
    int m = lane&15, quad = lane>>4;
    int orow = lane>>2, oq = lane&3;
    int r0 = blockIdx.x*16;
    int row = r0 + m;

    // ---- phase 1: this wave produces r cols [wave*256, wave*256+256)
    #pragma unroll
    for (int nn=0; nn<4; ++nn){
        int n = wave*4 + nn;
        float sc = (n < 6) ? scale[row] : 0.f;
        f32x4 acc[4];
        #pragma unroll
        for (int c=0;c<4;++c) acc[c]=(f32x4)0.f;
        #pragma unroll
        for (int s=0;s<6;++s){
            int g0 = n*192 + s*32;
            short8 af;
            if (g0 < 1024){
                short8 hv = *(const short8*)(h + (size_t)(g0>>6)*P_ + (size_t)row*64 + (g0&63) + quad*8);
                #pragma unroll
                for (int j=0;j<8;++j) af[j] = (short)f2bf(bf2f((ushort_t)hv[j])*sc);
            } else if (g0 < 2048){
                int ge = g0 - 1024;
                af = *(const short8*)(e + (size_t)(ge>>6)*P_ + (size_t)row*64 + (ge&63) + quad*8);
            } else {
                int ge = g0 - 2048;
                if ((row & (T_-1)) == 0) af = short8{0,0,0,0,0,0,0,0};
                else af = *(const short8*)(e + (size_t)(ge>>6)*P_ + (size_t)(row-1)*64 + (ge&63) + quad*8);
            }
            #pragma unroll
            for (int c=0;c<4;++c){
                short8 bw = *(const short8*)(wpost + n*(64*192) + (c*16+m)*192 + s*32 + quad*8);
                acc[c] = mfma16(af, bw, acc[c]);
            }
        }
        #pragma unroll
        for (int c=0;c<4;++c)
            #pragma unroll
            for (int rr=0;rr<4;++rr)
                r_lds[quad*4+rr][n*64 + c*16 + m] = f2bf(silu_f(acc[c][rr]));
    }
    __syncthreads();

    // ---- phase 2: rlow partial (this wave: K-slice [wave*256, wave*256+256))
    {
        f32x4 racc[4];
        #pragma unroll
        for (int c=0;c<4;++c) racc[c]=(f32x4)0.f;
        #pragma unroll
        for (int s=0;s<8;++s){
            int col = wave*256 + s*32;
            short8 a = *(const short8*)&r_lds[m][col + quad*8];
            #pragma unroll
            for (int c=0;c<4;++c){
                short8 b = *(const short8*)(lrB + (c*16+m)*1024 + col + quad*8);
                racc[c] = mfma16(a, b, racc[c]);
            }
        }
        #pragma unroll
        for (int c=0;c<4;++c)
            #pragma unroll
            for (int rr=0;rr<4;++rr)
                sacc[wave][quad*4+rr][c*16+m] = racc[c][rr];
    }
    __syncthreads();
    {
        int rrow = threadIdx.x>>4;          // 0..15
        int col4 = (threadIdx.x&15)*4;      // 0..60
        float4 v0 = *(const float4*)&sacc[0][rrow][col4];
        float4 v1 = *(const float4*)&sacc[1][rrow][col4];
        float4 v2 = *(const float4*)&sacc[2][rrow][col4];
        float4 v3 = *(const float4*)&sacc[3][rrow][col4];
        rl_lds[rrow][col4+0] = f2bf(v0.x+v1.x+v2.x+v3.x);
        rl_lds[rrow][col4+1] = f2bf(v0.y+v1.y+v2.y+v3.y);
        rl_lds[rrow][col4+2] = f2bf(v0.z+v1.z+v2.z+v3.z);
        rl_lds[rrow][col4+3] = f2bf(v0.w+v1.w+v2.w+v3.w);
    }
    __syncthreads();

    // ---- phase 3: out for this wave's 4 n-blocks
    short8 al0 = *(const short8*)&rl_lds[m][quad*8];
    short8 al1 = *(const short8*)&rl_lds[m][32 + quad*8];
    #pragma unroll
    for (int nn=0; nn<4; ++nn){
        int n = wave*4 + nn;
        short8 wl[2][4], la[4][2];
        #pragma unroll
        for (int c=0;c<4;++c)
            #pragma unroll
            for (int s=0;s<2;++s){
                wl[s][c] = *(const short8*)(wloc + n*4096 + (c*16+m)*64 + s*32 + quad*8);
                la[c][s] = *(const short8*)(lrA + (size_t)(n*64 + c*16 + m)*64 + s*32 + quad*8);
            }
        const float* xb = x + (size_t)(r0+orow)*D_ + n*64;
        float4 xv[4];
        #pragma unroll
        for (int it=0;it<4;++it) xv[it] = *(const float4*)(xb + (it*4+oq)*4);

        short8 ar0 = *(const short8*)&r_lds[m][n*64 + quad*8];
        short8 ar1 = *(const short8*)&r_lds[m][n*64 + 32 + quad*8];
        f32x4 acc[4];
        #pragma unroll
        for (int c=0;c<4;++c){
            acc[c]=(f32x4)0.f;
            acc[c]=mfma16(al0, la[c][0], acc[c]);
            acc[c]=mfma16(al1, la[c][1], acc[c]);
            acc[c]=mfma16(ar0, wl[0][c], acc[c]);
            acc[c]=mfma16(ar1, wl[1][c], acc[c]);
        }
        // stage via sacc[wave] (wave-private, in-wave LDS ordering; safe after the
        // post-reduce __syncthreads above)
        #pragma unroll
        for (int c=0;c<4;++c)
            #pragma unroll
            for (int rr=0;rr<4;++rr)
                sacc[wave][quad*4+rr][c*16+m] = acc[c][rr];
        float* ob = out + (size_t)(r0+orow)*D_ + n*64;
        #pragma unroll
        for (int it=0;it<4;++it){
            float4 v = *(const float4*)&sacc[wave][orow][(it*4+oq)*4];
            v.x += xv[it].x; v.y += xv[it].y; v.z += xv[it].z; v.w += xv[it].w;
            *(float4*)(ob + (it*4+oq)*4) = v;
        }
    }
}

extern "C" void kernel_launch(void* const* d_in, const int* in_sizes, int n_in,
                              void* d_out, int out_size, void* d_ws, size_t ws_size,
                              hipStream_t stream) {
    const float* x         = (const float*)d_in[0];
    const int*   active_k  = (const int*)  d_in[1];
    const float* b_seq_w   = (const float*)d_in[2];
    const float* b_depth_w = (const float*)d_in[3];
    const float* w_post_w  = (const float*)d_in[4];
    const float* w_local_w = (const float*)d_in[5];
    const float* lr_A      = (const float*)d_in[6];
    const float* lr_B      = (const float*)d_in[7];
    const float* logA_seq  = (const float*)d_in[8];
    const float* logdt_seq = (const float*)d_in[9];
    const float* logA_dep  = (const float*)d_in[10];
    const float* logdt_dep = (const float*)d_in[11];

    float* ws    = (float*)d_ws;
    float* carry = ws;                               // B_*NCH_*D_ = 262144
    float* aseq  = carry + (size_t)B_*NCH_*D_;
    float* apowC = aseq + D_;
    float* gain  = apowC + D_;
    float* scale = gain + D_;                        // R_ floats
    ushort_t* ub       = (ushort_t*)(scale + R_);
    ushort_t* e_bf     = ub;                         // R_*D_ (tiled 16 planes)
    ushort_t* hsum_bf  = e_bf + (size_t)R_*D_;       // R_*D_ (tiled)
    ushort_t* h_bf     = hsum_bf + (size_t)R_*D_;    // R_*D_ (tiled)
    ushort_t* wseq_bf  = h_bf + (size_t)R_*D_;       // 65536
    ushort_t* wdep_bf  = wseq_bf + 65536;
    ushort_t* wpost_bf = wdep_bf + 65536;            // 196608
    ushort_t* wloc_bf  = wpost_bf + 196608;
    ushort_t* lrA_bf   = wloc_bf + 65536;
    ushort_t* lrB_bf   = lrA_bf + 65536;

    prep_k<<<(524288 + D_ + 255)/256, 256, 0, stream>>>(
        b_seq_w, b_depth_w, w_post_w, w_local_w, lr_A, lr_B,
        wseq_bf, wdep_bf, wpost_bf, wloc_bf, lrA_bf, lrB_bf,
        logA_seq, logdt_seq, logA_dep, logdt_dep, active_k, aseq, apowC, gain);

    rmsbf_k<<<R_, 256, 0, stream>>>(x, e_bf);
    bd2s_k <<<dim3(R_/256, 16), 256, 0, stream>>>(e_bf, wseq_bf, wdep_bf, gain, aseq,
                                                  hsum_bf, carry);
    scan2_k<<<(B_*D_)/256, 256, 0, stream>>>(carry, apowC);
    scan3_k<<<(B_*NCH_*D_/8)/256, 256, 0, stream>>>(hsum_bf, aseq, carry, h_bf);
    scale_k<<<R_/4, 256, 0, stream>>>(h_bf, scale);
    por_k  <<<R_/16, 256, 0, stream>>>(x, h_bf, scale, e_bf, wpost_bf, lrB_bf, wloc_bf, lrA_bf,
                                       (float*)d_out);
}

// Round 7
// 271.582 us; speedup vs baseline: 1.1820x; 1.1820x over previous
//
#include <hip/hip_runtime.h>

#define B_ 4
#define T_ 4096
#define D_ 1024
#define R_ (B_*T_)
#define CHUNK_ 64
#define NCH_ (T_/CHUNK_)
#define EPS_ 1.1920929e-07f

typedef unsigned short ushort_t;
typedef __attribute__((ext_vector_type(8))) short short8;
typedef __attribute__((ext_vector_type(4))) float f32x4;

__device__ __forceinline__ float silu_f(float v){ return v / (1.0f + __expf(-v)); }

__device__ __forceinline__ ushort_t f2bf(float f){
    unsigned u = __float_as_uint(f);
    unsigned r = u + 0x7fffu + ((u>>16)&1u);
    return (ushort_t)(r>>16);
}
__device__ __forceinline__ float bf2f(ushort_t s){ return __uint_as_float(((unsigned)s)<<16); }

__device__ __forceinline__ f32x4 mfma16(short8 a, short8 b, f32x4 c){
    return __builtin_amdgcn_mfma_f32_16x16x32_bf16(a, b, c, 0, 0, 0);
}

// ---------------- prep: weight cvt (bf16) + scalar setup + apow table ----------------
__global__ void prep_k(const float* __restrict__ s0, const float* __restrict__ s1,
                       const float* __restrict__ s2, const float* __restrict__ s3,
                       const float* __restrict__ s4, const float* __restrict__ s5,
                       ushort_t* __restrict__ d0, ushort_t* __restrict__ d1,
                       ushort_t* __restrict__ d2, ushort_t* __restrict__ d3,
                       ushort_t* __restrict__ d4, ushort_t* __restrict__ d5,
                       const float* __restrict__ logA_seq, const float* __restrict__ logdt_seq,
                       const float* __restrict__ logA_dep, const float* __restrict__ logdt_dep,
                       const int* __restrict__ active_k,
                       float* __restrict__ aseq, float* __restrict__ apowC,
                       float* __restrict__ gain, float* __restrict__ apowtab){
    int i = blockIdx.x*256 + threadIdx.x;
    if      (i < 65536)   d0[i] = f2bf(s0[i]);
    else if (i < 131072)  d1[i-65536] = f2bf(s1[i-65536]);
    else if (i < 327680)  d2[i-131072] = f2bf(s2[i-131072]);
    else if (i < 393216)  d3[i-327680] = f2bf(s3[i-327680]);
    else if (i < 458752)  d4[i-393216] = f2bf(s4[i-393216]);
    else if (i < 524288)  d5[i-458752] = f2bf(s5[i-458752]);
    else if (i < 524288 + D_){
        int d = i - 524288;
        float K = (float)(*active_k);
        float a = expf(-expf(logA_seq[d]) * expf(logdt_seq[d]));
        a = fmaxf(a, 1e-6f);
        aseq[d] = a;
        apowC[d] = powf(a, (float)CHUNK_);
        // apowtab[s][d] = a^(s+1), s = row index within 64-chunk
        float ap = a;
        for (int s2=0;s2<CHUNK_;++s2){ apowtab[s2*D_ + d] = ap; ap *= a; }
        float g;
        if (d < 128) {
            g = K;
        } else {
            float ad = expf(-expf(logA_dep[d-128]) * expf(logdt_dep[d-128]));
            float om = 1.0f - ad;
            if (fabsf(om) < 1e-6f) g = K;
            else g = (1.0f - powf(ad, K)) / fmaxf(om, 1e-8f);
        }
        gain[d] = g;
    }
}

// ---------------- rms_norm(x) -> e bf16 ----------------
__global__ __launch_bounds__(256) void rmsbf_k(const float* __restrict__ x, ushort_t* __restrict__ e){
    int row = blockIdx.x;
    int tid = threadIdx.x;
    float4 v = ((const float4*)(x + (size_t)row*D_))[tid];
    float ss = v.x*v.x + v.y*v.y + v.z*v.z + v.w*v.w;
    for (int off=32; off; off>>=1) ss += __shfl_down(ss, off, 64);
    __shared__ float red[4];
    if ((tid&63)==0) red[tid>>6] = ss;
    __syncthreads();
    float tot = red[0]+red[1]+red[2]+red[3];
    float scale = 1.0f / sqrtf(tot*(1.0f/D_) + EPS_);
    ushort4 o;
    o.x = f2bf(v.x*scale); o.y = f2bf(v.y*scale); o.z = f2bf(v.z*scale); o.w = f2bf(v.w*scale);
    ((ushort4*)(e + (size_t)row*D_))[tid] = o;
}

// ---------------- bd2s: blockdiags + fused local chunk scan ----------------
__global__ __launch_bounds__(256) void bd2s_k(const ushort_t* __restrict__ e,
        const ushort_t* __restrict__ wseq, const ushort_t* __restrict__ wdep,
        const float* __restrict__ gain, const float* __restrict__ aseq,
        ushort_t* __restrict__ hsum, float* __restrict__ carry){
    __shared__ __align__(16) ushort_t sd[4][16][72];
    __shared__ __align__(16) ushort_t sh[4][16][72];
    int wave = threadIdx.x>>6, lane = threadIdx.x&63;
    int m = lane&15, quad = lane>>4;
    int orow = lane>>2, oq = lane&3;
    int n = blockIdx.y;
    int chunk0 = blockIdx.x*256 + wave*64;

    short8 bs[2][4], bd[2][4];
    #pragma unroll
    for (int s=0;s<2;++s)
        #pragma unroll
        for (int c=0;c<4;++c){
            bs[s][c] = *(const short8*)(wseq + n*4096 + (c*16+m)*64 + s*32 + quad*8);
            bd[s][c] = *(const short8*)(wdep + n*4096 + (c*16+m)*64 + s*32 + quad*8);
        }
    float g[4];
    #pragma unroll
    for (int c=0;c<4;++c) g[c] = gain[n*64 + c*16 + m];

    float a = aseq[n*64 + lane];
    float hh = 0.f;

    #pragma unroll
    for (int t=0;t<4;++t){
        int r0 = chunk0 + t*16;
        const ushort_t* ab = e + (size_t)(r0+m)*D_ + n*64 + quad*8;
        short8 a0 = *(const short8*)ab;
        short8 a1 = *(const short8*)(ab + 32);
        f32x4 accs[4], accd[4];
        #pragma unroll
        for (int c=0;c<4;++c){
            accs[c]=(f32x4)0.f; accd[c]=(f32x4)0.f;
            accs[c]=mfma16(a0, bs[0][c], accs[c]);
            accd[c]=mfma16(a0, bd[0][c], accd[c]);
            accs[c]=mfma16(a1, bs[1][c], accs[c]);
            accd[c]=mfma16(a1, bd[1][c], accd[c]);
        }
        #pragma unroll
        for (int c=0;c<4;++c)
            #pragma unroll
            for (int r=0;r<4;++r){
                sd[wave][quad*4+r][c*16+m] = f2bf(silu_f(accs[c][r]));
                sh[wave][quad*4+r][c*16+m] = f2bf(g[c]*silu_f(accd[c][r]));
            }
        #pragma unroll
        for (int s=0;s<16;++s){
            hh = fmaf(a, hh, bf2f(sd[wave][s][lane]));
            sd[wave][s][lane] = f2bf(hh + bf2f(sh[wave][s][lane]));
        }
        ushort_t* db = hsum + (size_t)(r0+orow)*D_ + n*64;
        #pragma unroll
        for (int it=0;it<2;++it)
            *(short8*)(db + (it*4+oq)*8) = *(const short8*)&sd[wave][orow][(it*4+oq)*8];
    }
    carry[(size_t)(chunk0>>6)*D_ + n*64 + lane] = hh;
}

// ---------------- scan2: serial prefix over chunk carries ----------------
__global__ __launch_bounds__(256) void scan2_k(float* __restrict__ carry, const float* __restrict__ apowC){
    int tid = blockIdx.x*256 + threadIdx.x;      // B_*D_ threads
    int d = tid & (D_-1);
    int b = tid >> 10;
    float aC = apowC[d];
    float pref = 0.f;
    for (int c=0;c<NCH_;++c){
        size_t idx = (size_t)(b*NCH_+c)*D_ + d;
        float s = carry[idx];
        carry[idx] = pref;
        pref = fmaf(aC, pref, s);
    }
}

// ---------------- scan3s: hn = rmsnorm(hsum + P*a^(s+1)) in ONE pass ----------------
// block = 8 rows x 1024 cols (2048 blocks). h kept in registers; row-RMS via
// wave shuffle + tiny LDS; writes hn = h*scale directly. Replaces scan3+scale+hn.
__global__ __launch_bounds__(256) void scan3s_k(const ushort_t* __restrict__ hsum,
                                                const float* __restrict__ aseq,
                                                const float* __restrict__ carry,
                                                const float* __restrict__ apowtab,
                                                ushort_t* __restrict__ hn){
    __shared__ float part[4][4];
    __shared__ float scl[8];
    int tid = threadIdx.x;
    int lane = tid & 63, wave = tid >> 6;
    int cg = tid & 127;        // col group (8 cols)
    int rp = tid >> 7;         // row parity (0/1)
    int d0 = cg*8;
    int row0 = blockIdx.x*8;   // 8 rows, all within one 64-chunk
    int bc = row0 >> 6;
    int s0 = row0 & 63;

    float a2[8], P[8], apow[8];
    #pragma unroll
    for (int j=0;j<8;++j){
        float aj = aseq[d0+j];
        a2[j] = aj*aj;
        P[j]  = carry[(size_t)bc*D_ + d0 + j];
        apow[j] = apowtab[(size_t)(s0 + rp)*D_ + d0 + j];   // a^(s+1) at first row
    }

    float hf[4][8];
    #pragma unroll
    for (int i=0;i<4;++i){
        int row = row0 + i*2 + rp;
        short8 v = *(const short8*)(hsum + (size_t)row*D_ + d0);
        float ss = 0.f;
        #pragma unroll
        for (int j=0;j<8;++j){
            float f = bf2f((ushort_t)v[j]) + P[j]*apow[j];
            hf[i][j] = f;
            ss += f*f;
            apow[j] *= a2[j];
        }
        for (int off=32; off; off>>=1) ss += __shfl_down(ss, off, 64);
        if (lane==0) part[wave][i] = ss;
    }
    __syncthreads();
    if (tid < 8){
        int r = tid;                 // row index within block
        int rr = r & 1, ii = r >> 1;
        float sum = part[rr*2][ii] + part[rr*2+1][ii];
        scl[r] = rsqrtf(sum*(1.0f/D_) + EPS_);
    }
    __syncthreads();
    #pragma unroll
    for (int i=0;i<4;++i){
        int rloc = i*2 + rp;
        float sc = scl[rloc];
        short8 o;
        #pragma unroll
        for (int j=0;j<8;++j) o[j] = (short)f2bf(hf[i][j]*sc);
        *(short8*)(hn + (size_t)(row0 + rloc)*D_ + d0) = o;
    }
}

// ---------------- post: r = silu(concat[hn,e,eshift] @ wpost^T) bf16 ----------------
// s-loop outermost (unroll 1): 4 weight fragments live at a time.
__global__ __launch_bounds__(256) void post_k(const ushort_t* __restrict__ hn,
                                              const ushort_t* __restrict__ e,
                                              const ushort_t* __restrict__ wpost, ushort_t* __restrict__ rout){
    __shared__ __align__(16) ushort_t st[4][16][72];
    int wave = threadIdx.x>>6, lane = threadIdx.x&63;
    int m = lane&15, quad = lane>>4;
    int orow = lane>>2, oq = lane&3;
    int n = blockIdx.y;
    int row0 = blockIdx.x*128 + wave*32 + m;

    f32x4 acc[2][4];
    #pragma unroll
    for (int t=0;t<2;++t)
        #pragma unroll
        for (int c=0;c<4;++c) acc[t][c]=(f32x4)0.f;

    #pragma unroll 1
    for (int s=0;s<6;++s){
        int g0 = n*192 + s*32;
        short8 bw[4];
        #pragma unroll
        for (int c=0;c<4;++c)
            bw[c] = *(const short8*)(wpost + n*(64*192) + (c*16+m)*192 + s*32 + quad*8);
        #pragma unroll
        for (int t=0;t<2;++t){
            int row = row0 + t*16;
            short8 af;
            if (g0 < 1024){
                af = *(const short8*)(hn + (size_t)row*D_ + g0 + quad*8);
            } else if (g0 < 2048){
                af = *(const short8*)(e + (size_t)row*D_ + (g0-1024) + quad*8);
            } else {
                if ((row & (T_-1)) == 0) af = short8{0,0,0,0,0,0,0,0};
                else af = *(const short8*)(e + (size_t)(row-1)*D_ + (g0-2048) + quad*8);
            }
            #pragma unroll
            for (int c=0;c<4;++c)
                acc[t][c] = mfma16(af, bw[c], acc[t][c]);
        }
    }
    #pragma unroll
    for (int t=0;t<2;++t){
        int r0 = blockIdx.x*128 + wave*32 + t*16;
        #pragma unroll
        for (int c=0;c<4;++c)
            #pragma unroll
            for (int r=0;r<4;++r)
                st[wave][quad*4+r][c*16+m] = f2bf(silu_f(acc[t][c][r]));
        ushort_t* db = rout + (size_t)(r0+orow)*D_ + n*64;
        #pragma unroll
        for (int it=0;it<2;++it)
            *(short8*)(db + (it*4+oq)*8) = *(const short8*)&st[wave][orow][(it*4+oq)*8];
    }
}

// ---------------- rlow = r @ lrB^T (K=1024 -> 64) bf16, split-K over 4 waves ----------------
__global__ __launch_bounds__(256) void rlow_k(const ushort_t* __restrict__ r, const ushort_t* __restrict__ lrB,
                                              ushort_t* __restrict__ rlow){
    __shared__ __align__(16) float sacc[4][16][68];
    int wave = threadIdx.x>>6, lane = threadIdx.x&63;
    int m = lane&15, quad = lane>>4;
    int r0 = blockIdx.x*16;
    f32x4 acc[4];
    #pragma unroll
    for (int c=0;c<4;++c) acc[c]=(f32x4)0.f;
    const ushort_t* ab = r + (size_t)(r0+m)*D_ + wave*256 + quad*8;
    #pragma unroll
    for (int s=0;s<8;++s){
        short8 a = *(const short8*)(ab + s*32);
        #pragma unroll
        for (int c=0;c<4;++c){
            short8 b = *(const short8*)(lrB + (c*16+m)*1024 + wave*256 + s*32 + quad*8);
            acc[c] = mfma16(a, b, acc[c]);
        }
    }
    #pragma unroll
    for (int c=0;c<4;++c)
        #pragma unroll
        for (int r2=0;r2<4;++r2)
            sacc[wave][quad*4+r2][c*16+m] = acc[c][r2];
    __syncthreads();
    int row  = threadIdx.x>>4;        // 0..15
    int col4 = (threadIdx.x&15)*4;    // 0..60 step 4
    float4 v0 = *(const float4*)&sacc[0][row][col4];
    float4 v1 = *(const float4*)&sacc[1][row][col4];
    float4 v2 = *(const float4*)&sacc[2][row][col4];
    float4 v3 = *(const float4*)&sacc[3][row][col4];
    ushort4 o;
    o.x = f2bf(v0.x+v1.x+v2.x+v3.x);
    o.y = f2bf(v0.y+v1.y+v2.y+v3.y);
    o.z = f2bf(v0.z+v1.z+v2.z+v3.z);
    o.w = f2bf(v0.w+v1.w+v2.w+v3.w);
    *(ushort4*)(rlow + (size_t)(r0+row)*64 + col4) = o;
}

// ---------------- out = x + r@wloc^T + rlow@lrA^T ----------------
__global__ __launch_bounds__(256) void out_k(const float* __restrict__ x, const ushort_t* __restrict__ r,
        const ushort_t* __restrict__ rlow, const ushort_t* __restrict__ wloc, const ushort_t* __restrict__ lrA,
        float* __restrict__ out){
    __shared__ __align__(16) float st[4][16][68];
    int wave = threadIdx.x>>6, lane = threadIdx.x&63;
    int m = lane&15, quad = lane>>4;
    int orow = lane>>2, oq = lane&3;
    int n = blockIdx.y;

    short8 wl[2][4], la[4][2];
    #pragma unroll
    for (int c=0;c<4;++c)
        #pragma unroll
        for (int s=0;s<2;++s){
            wl[s][c] = *(const short8*)(wloc + n*4096 + (c*16+m)*64 + s*32 + quad*8);
            la[c][s] = *(const short8*)(lrA + (size_t)(n*64 + c*16 + m)*64 + s*32 + quad*8);
        }
    #pragma unroll
    for (int t=0;t<2;++t){
        int r0 = blockIdx.x*128 + wave*32 + t*16;
        const float* xb = x + (size_t)(r0+orow)*D_ + n*64;
        float4 xv[4];
        #pragma unroll
        for (int it=0;it<4;++it) xv[it] = *(const float4*)(xb + (it*4+oq)*4);

        const ushort_t* lb = rlow + (size_t)(r0+m)*64 + quad*8;
        short8 al0 = *(const short8*)lb;
        short8 al1 = *(const short8*)(lb + 32);
        const ushort_t* ab = r + (size_t)(r0+m)*D_ + n*64 + quad*8;
        short8 ar0 = *(const short8*)ab;
        short8 ar1 = *(const short8*)(ab + 32);
        f32x4 acc[4];
        #pragma unroll
        for (int c=0;c<4;++c){
            acc[c]=(f32x4)0.f;
            acc[c]=mfma16(al0, la[c][0], acc[c]);
            acc[c]=mfma16(al1, la[c][1], acc[c]);
            acc[c]=mfma16(ar0, wl[0][c], acc[c]);
            acc[c]=mfma16(ar1, wl[1][c], acc[c]);
        }
        #pragma unroll
        for (int c=0;c<4;++c)
            #pragma unroll
            for (int r2=0;r2<4;++r2)
                st[wave][quad*4+r2][c*16+m] = acc[c][r2];
        float* ob = out + (size_t)(r0+orow)*D_ + n*64;
        #pragma unroll
        for (int it=0;it<4;++it){
            float4 v = *(const float4*)&st[wave][orow][(it*4+oq)*4];
            v.x += xv[it].x; v.y += xv[it].y; v.z += xv[it].z; v.w += xv[it].w;
            *(float4*)(ob + (it*4+oq)*4) = v;
        }
    }
}

extern "C" void kernel_launch(void* const* d_in, const int* in_sizes, int n_in,
                              void* d_out, int out_size, void* d_ws, size_t ws_size,
                              hipStream_t stream) {
    const float* x         = (const float*)d_in[0];
    const int*   active_k  = (const int*)  d_in[1];
    const float* b_seq_w   = (const float*)d_in[2];
    const float* b_depth_w = (const float*)d_in[3];
    const float* w_post_w  = (const float*)d_in[4];
    const float* w_local_w = (const float*)d_in[5];
    const float* lr_A      = (const float*)d_in[6];
    const float* lr_B      = (const float*)d_in[7];
    const float* logA_seq  = (const float*)d_in[8];
    const float* logdt_seq = (const float*)d_in[9];
    const float* logA_dep  = (const float*)d_in[10];
    const float* logdt_dep = (const float*)d_in[11];

    float* ws      = (float*)d_ws;
    float* carry   = ws;                             // B_*NCH_*D_ = 262144
    float* aseq    = carry + (size_t)B_*NCH_*D_;
    float* apowC   = aseq + D_;
    float* gain    = apowC + D_;
    float* apowtab = gain + D_;                      // CHUNK_*D_ = 65536
    ushort_t* ub       = (ushort_t*)(apowtab + (size_t)CHUNK_*D_);
    ushort_t* e_bf     = ub;                         // R_*D_
    ushort_t* hsum_bf  = e_bf + (size_t)R_*D_;       // R_*D_ (scanned drive + hdep)
    ushort_t* hn_bf    = hsum_bf + (size_t)R_*D_;    // R_*D_ (normalized h)
    ushort_t* r_bf     = hn_bf + (size_t)R_*D_;      // R_*D_
    ushort_t* rlow_bf  = r_bf + (size_t)R_*D_;       // R_*64
    ushort_t* wseq_bf  = rlow_bf + (size_t)R_*64;    // 65536
    ushort_t* wdep_bf  = wseq_bf + 65536;
    ushort_t* wpost_bf = wdep_bf + 65536;            // 196608
    ushort_t* wloc_bf  = wpost_bf + 196608;
    ushort_t* lrA_bf   = wloc_bf + 65536;
    ushort_t* lrB_bf   = lrA_bf + 65536;

    prep_k<<<(524288 + D_ + 255)/256, 256, 0, stream>>>(
        b_seq_w, b_depth_w, w_post_w, w_local_w, lr_A, lr_B,
        wseq_bf, wdep_bf, wpost_bf, wloc_bf, lrA_bf, lrB_bf,
        logA_seq, logdt_seq, logA_dep, logdt_dep, active_k, aseq, apowC, gain, apowtab);

    rmsbf_k <<<R_, 256, 0, stream>>>(x, e_bf);
    bd2s_k  <<<dim3(R_/256, 16), 256, 0, stream>>>(e_bf, wseq_bf, wdep_bf, gain, aseq,
                                                   hsum_bf, carry);
    scan2_k <<<(B_*D_)/256, 256, 0, stream>>>(carry, apowC);
    scan3s_k<<<R_/8, 256, 0, stream>>>(hsum_bf, aseq, carry, apowtab, hn_bf);
    post_k  <<<dim3(R_/128, 16), 256, 0, stream>>>(hn_bf, e_bf, wpost_bf, r_bf);
    rlow_k  <<<R_/16, 256, 0, stream>>>(r_bf, lrB_bf, rlow_bf);
    out_k   <<<dim3(R_/128, 16), 256, 0, stream>>>(x, r_bf, rlow_bf, wloc_bf, lrA_bf, (float*)d_out);
}